// Round 10
// baseline (1568.325 us; speedup 1.0000x reference)
//
#include <hip/hip_runtime.h>
#include <hip/hip_bf16.h>
#include <float.h>

// image [16,3,256,256] -> conv1(3->192,s2)+relu -> conv2(192->384,s2)+relu
// -> conv3(384->768,s2) -> feats [16384,768] -> argmin over 8192 codes -> gather.
// conv2/conv3/VQ: split-FP16 MFMA GEMMs (x = hi + lo, dot = ah*bh + ah*bl + al*bh,
// per-term error ~2^-22) on v_mfma_f32_32x32x16_f16 (2382 TF ceiling, half the
// instruction count of 16x16x32 for the same FLOPs). Staging: global_load_lds 16B,
// linear LDS dest, XOR swizzle (chunk ^= row&7) pre-applied to the global source.
// Launcher picks chunking by ws_size (big: conv2 2x8-img, conv3 all-16).

typedef __attribute__((ext_vector_type(16))) float f32x16;
typedef __attribute__((ext_vector_type(8))) _Float16 f16x8;
typedef __attribute__((ext_vector_type(8))) unsigned short u16x8;

__device__ __forceinline__ void split_f16(float x, unsigned short& hb, unsigned short& lb) {
    _Float16 h = (_Float16)x;                    // RNE fp32->fp16
    _Float16 l = (_Float16)(x - (float)h);       // residual, ~2^-12|x|
    hb = __builtin_bit_cast(unsigned short, h);
    lb = __builtin_bit_cast(unsigned short, l);
}

__device__ __forceinline__ void gload16(const void* g, const unsigned short* l) {
    typedef unsigned int __attribute__((address_space(1))) g_u32;
    typedef unsigned int __attribute__((address_space(3))) l_u32;
    __builtin_amdgcn_global_load_lds((const g_u32*)g, (l_u32*)l, 16, 0, 0);
}

// ------------------------------------------------------------- zero page
__global__ __launch_bounds__(256) void zero_kernel(unsigned short* z) {
    u16x8 v = {0, 0, 0, 0, 0, 0, 0, 0};
    *(u16x8*)&z[threadIdx.x * 8] = v;           // 4 KB
}

// -------------------------------------------------- weight reorder+split
__global__ __launch_bounds__(256) void reorder_w_kernel(
    const float* __restrict__ w, unsigned short* __restrict__ wh,
    unsigned short* __restrict__ wl, int COUT, int CIN)
{
    const int t = blockIdx.x * 256 + threadIdx.x;
    const int c8n = CIN / 8;
    const int total = COUT * 9 * c8n;
    if (t >= total) return;
    const int c8 = t % c8n;
    const int tap = (t / c8n) % 9;
    const int o = t / (9 * c8n);
    u16x8 vh, vl;
#pragma unroll
    for (int k = 0; k < 8; ++k) {
        const int c = c8 * 8 + k;
        unsigned short hb, lb;
        split_f16(w[((size_t)o * CIN + c) * 9 + tap], hb, lb);
        vh[k] = hb; vl[k] = lb;
    }
    const size_t dst = ((size_t)o * 9 + tap) * CIN + c8 * 8;
    *(u16x8*)&wh[dst] = vh;
    *(u16x8*)&wl[dst] = vl;
}

// --------------------------------- conv1: direct fp32, NHWC fp16 hi/lo out
template <int CIN, int COUT, int HIN, int HOUT>
__global__ __launch_bounds__(256) void conv1_direct(
    const float* __restrict__ in,   // [nb][CIN][HIN][HIN] (chunk-local)
    const float* __restrict__ w, const float* __restrict__ bias,
    unsigned short* __restrict__ ah, unsigned short* __restrict__ al, int nb)
{
    constexpr int WIN = HIN, WOUT = HOUT;
    constexpr int NXT = WOUT / 4;
    constexpr int NOT = COUT / 8;
    int t = blockIdx.x * 256 + threadIdx.x;
    const int total = nb * NOT * HOUT * NXT;
    if (t >= total) return;

    const int xt = t % NXT;
    const int y  = (t / NXT) % HOUT;
    int ot = (t / (NXT * HOUT)) % NOT;          // wave-uniform
    int bl = t / (NXT * HOUT * NOT);            // wave-uniform
    ot = __builtin_amdgcn_readfirstlane(ot);
    bl = __builtin_amdgcn_readfirstlane(bl);

    const int x0 = xt * 4, o0 = ot * 8;
    float acc[8][4];
#pragma unroll
    for (int i = 0; i < 8; ++i) {
        float bv = bias[o0 + i];
#pragma unroll
        for (int j = 0; j < 4; ++j) acc[i][j] = bv;
    }

    const float* inb = in + (size_t)bl * CIN * HIN * WIN;
    const float* wb  = w + (size_t)o0 * CIN * 9;

    for (int c = 0; c < CIN; ++c) {
        const float* inc = inb + (size_t)c * HIN * WIN;
#pragma unroll
        for (int ky = 0; ky < 3; ++ky) {
            const int iy = 2 * y - 1 + ky;
            if ((unsigned)iy < (unsigned)HIN) {
                const float* row = inc + (size_t)iy * WIN;
                const int sx0 = 2 * x0 - 1;
                float xin[9];
                xin[0] = (sx0 >= 0) ? row[sx0] : 0.f;
#pragma unroll
                for (int k = 1; k < 9; ++k) xin[k] = row[sx0 + k];
#pragma unroll
                for (int i = 0; i < 8; ++i) {
                    const float* wr = wb + ((size_t)i * CIN + c) * 9 + ky * 3;
                    const float w0 = wr[0], w1 = wr[1], w2 = wr[2];
#pragma unroll
                    for (int j = 0; j < 4; ++j)
                        acc[i][j] = fmaf(w0, xin[2 * j],
                                    fmaf(w1, xin[2 * j + 1],
                                    fmaf(w2, xin[2 * j + 2], acc[i][j])));
                }
            }
        }
    }

#pragma unroll
    for (int j = 0; j < 4; ++j) {
        u16x8 vh, vl;
#pragma unroll
        for (int i = 0; i < 8; ++i) {
            unsigned short hb, lb;
            split_f16(fmaxf(acc[i][j], 0.f), hb, lb);
            vh[i] = hb; vl[i] = lb;
        }
        const size_t m = (size_t)bl * (HOUT * WOUT) + (size_t)y * WOUT + x0 + j;
        *(u16x8*)&ah[m * COUT + o0] = vh;
        *(u16x8*)&al[m * COUT + o0] = vl;
    }
}

// --------------------------- conv2/conv3: implicit-GEMM split-fp16 MFMA
// Block 128(M) x 128(N); 4 waves, each 64x64 = 2x2 frags of 32x32x16.
template <int CIN, int COUT, int HIN, int HOUT, int LOGW, int LOGHW, bool RELU>
__global__ __launch_bounds__(256) void conv_gemm(
    const unsigned short* __restrict__ inh, const unsigned short* __restrict__ inl,
    const unsigned short* __restrict__ wrh, const unsigned short* __restrict__ wrl,
    const float* __restrict__ bias,
    unsigned short* __restrict__ outh, unsigned short* __restrict__ outl,
    const unsigned short* __restrict__ zeros)
{
    constexpr int WIN = HIN, WOUT = HOUT;
    constexpr int KCPT = CIN / 64;
    constexpr int NSTEP = 9 * KCPT;

    __shared__ unsigned short lds[32768];       // 64 KB
    unsigned short* As_h = lds;
    unsigned short* As_l = lds + 8192;
    unsigned short* Bs_h = lds + 16384;
    unsigned short* Bs_l = lds + 24576;

    const int tid  = threadIdx.x;
    const int lane = tid & 63;
    const int wid  = tid >> 6;
    const int ntile = blockIdx.x, mtile = blockIdx.y;
    const int m0 = mtile * 128, n0 = ntile * 128;
    const int wm = wid >> 1, wn = wid & 1;

    int aoff0[4], boff0[4], yv[4], xv[4], dstb[4];
#pragma unroll
    for (int p = 0; p < 4; ++p) {
        const int s = wid * 64 + p * 256 + lane;   // slot 0..1023
        const int r = s >> 3;                       // row 0..127
        const int cl = (s & 7) ^ (r & 7);           // logical k-chunk
        const int m = m0 + r;
        const int b = m >> LOGHW;
        const int y = (m >> LOGW) & (HOUT - 1);
        const int x = m & (WOUT - 1);
        yv[p] = y; xv[p] = x;
        aoff0[p] = ((b * HIN + 2 * y) * WIN + 2 * x) * CIN + cl * 8;
        boff0[p] = (n0 + r) * 9 * CIN + cl * 8;
        dstb[p] = (wid * 64 + p * 256) * 8;
    }

    f32x16 acc[2][2];
#pragma unroll
    for (int i = 0; i < 2; ++i)
#pragma unroll
        for (int j = 0; j < 2; ++j)
#pragma unroll
            for (int r = 0; r < 16; ++r) acc[i][j][r] = 0.f;

    for (int ks = 0; ks < NSTEP; ++ks) {
        const int tap = ks / KCPT;
        const int c0 = (ks % KCPT) * 64;
        const int ky = tap / 3, kx = tap - ky * 3;
        const int doff = ((ky - 1) * WIN + (kx - 1)) * CIN + c0;

#pragma unroll
        for (int p = 0; p < 4; ++p) {
            const bool valid = !((yv[p] == 0 && ky == 0) || (xv[p] == 0 && kx == 0));
            const unsigned short* sa_h = valid ? inh + (aoff0[p] + doff) : zeros;
            const unsigned short* sa_l = valid ? inl + (aoff0[p] + doff) : zeros;
            gload16(sa_h, As_h + dstb[p]);
            gload16(sa_l, As_l + dstb[p]);
            const int bo = boff0[p] + tap * CIN + c0;
            gload16(wrh + bo, Bs_h + dstb[p]);
            gload16(wrl + bo, Bs_l + dstb[p]);
        }
        __syncthreads();

#pragma unroll
        for (int kh = 0; kh < 4; ++kh) {            // K=16 slices
            const int cg = kh * 2 + (lane >> 5);
            f16x8 a_h[2], a_l[2], b_h[2], b_l[2];
#pragma unroll
            for (int i = 0; i < 2; ++i) {
                const int row = wm * 64 + i * 32 + (lane & 31);
                const int off = row * 64 + ((cg ^ (row & 7)) * 8);
                a_h[i] = *(const f16x8*)(As_h + off);
                a_l[i] = *(const f16x8*)(As_l + off);
            }
#pragma unroll
            for (int j = 0; j < 2; ++j) {
                const int col = wn * 64 + j * 32 + (lane & 31);
                const int off = col * 64 + ((cg ^ (col & 7)) * 8);
                b_h[j] = *(const f16x8*)(Bs_h + off);
                b_l[j] = *(const f16x8*)(Bs_l + off);
            }
            __builtin_amdgcn_s_setprio(1);
#pragma unroll
            for (int i = 0; i < 2; ++i)
#pragma unroll
                for (int j = 0; j < 2; ++j) {
                    acc[i][j] = __builtin_amdgcn_mfma_f32_32x32x16_f16(
                        a_h[i], b_h[j], acc[i][j], 0, 0, 0);
                    acc[i][j] = __builtin_amdgcn_mfma_f32_32x32x16_f16(
                        a_h[i], b_l[j], acc[i][j], 0, 0, 0);
                    acc[i][j] = __builtin_amdgcn_mfma_f32_32x32x16_f16(
                        a_l[i], b_h[j], acc[i][j], 0, 0, 0);
                }
            __builtin_amdgcn_s_setprio(0);
        }
        __syncthreads();
    }

    // epilogue: C/D layout row=(r&3)+8*(r>>2)+4*(lane>>5), col=lane&31
    float bv2[2];
#pragma unroll
    for (int j = 0; j < 2; ++j) bv2[j] = bias[n0 + wn * 64 + j * 32 + (lane & 31)];
#pragma unroll
    for (int i = 0; i < 2; ++i)
#pragma unroll
        for (int r = 0; r < 16; ++r) {
            const size_t m = m0 + wm * 64 + i * 32 + (r & 3) + 8 * (r >> 2) + 4 * (lane >> 5);
#pragma unroll
            for (int j = 0; j < 2; ++j) {
                const int n = n0 + wn * 64 + j * 32 + (lane & 31);
                float v = acc[i][j][r] + bv2[j];
                if (RELU) v = fmaxf(v, 0.f);
                unsigned short hb, lb;
                split_f16(v, hb, lb);
                outh[m * COUT + n] = hb;
                outl[m * COUT + n] = lb;
            }
        }
}

// -------------------------------------------- codebook split + norms
__global__ __launch_bounds__(256) void split_codebook_kernel(
    const float* __restrict__ cb, unsigned short* __restrict__ bh,
    unsigned short* __restrict__ bl, float* __restrict__ c2)
{
    const int v = blockIdx.x * 4 + (threadIdx.x >> 6);
    const int lane = threadIdx.x & 63;
    const float* row = cb + (size_t)v * 768;
    float s = 0.f;
#pragma unroll
    for (int t = 0; t < 12; ++t) {
        const int idx = lane + 64 * t;
        float x = row[idx];
        s = fmaf(x, x, s);
        unsigned short hb, lb;
        split_f16(x, hb, lb);
        bh[(size_t)v * 768 + idx] = hb;
        bl[(size_t)v * 768 + idx] = lb;
    }
#pragma unroll
    for (int off = 32; off >= 1; off >>= 1) s += __shfl_xor(s, off, 64);
    if (lane == 0) c2[v] = s;
}

// --------------------------------------- VQ: split-fp16 MFMA GEMM + argmin
__global__ __launch_bounds__(256) void vq_mfma_kernel(
    const unsigned short* __restrict__ Ah, const unsigned short* __restrict__ Al,
    const unsigned short* __restrict__ Bh, const unsigned short* __restrict__ Bl,
    const float* __restrict__ c2,
    float* __restrict__ pval, int* __restrict__ pidx)
{
    __shared__ unsigned short lds[32768];
    unsigned short* As_h = lds;
    unsigned short* As_l = lds + 8192;
    unsigned short* Bs_h = lds + 16384;
    unsigned short* Bs_l = lds + 24576;

    const int tid  = threadIdx.x;
    const int lane = tid & 63;
    const int wid  = tid >> 6;

    const int bid    = blockIdx.x;
    const int xcd    = bid & 7;
    const int local  = bid >> 3;
    const int msuper = local >> 5;
    const int idx5   = local & 31;
    const int mtile  = msuper * 4 + (idx5 & 3);
    const int ntile  = xcd * 8 + (idx5 >> 2);

    const int m0 = mtile * 128, n0 = ntile * 128;
    const int wm = wid >> 1, wn = wid & 1;

    f32x16 acc[2][2];
#pragma unroll
    for (int i = 0; i < 2; ++i)
#pragma unroll
        for (int j = 0; j < 2; ++j)
#pragma unroll
            for (int r = 0; r < 16; ++r) acc[i][j][r] = 0.f;

    for (int step = 0; step < 12; ++step) {
        const int kb = step * 64;
#pragma unroll
        for (int p = 0; p < 4; ++p) {
            const int s  = wid * 64 + p * 256 + lane;
            const int r  = s >> 3;
            const int cl = (s & 7) ^ (r & 7);
            const int dstbase = (wid * 64 + p * 256) * 8;
            const size_t ga = (size_t)(m0 + r) * 768 + kb + cl * 8;
            const size_t gb = (size_t)(n0 + r) * 768 + kb + cl * 8;
            gload16(Ah + ga, As_h + dstbase);
            gload16(Al + ga, As_l + dstbase);
            gload16(Bh + gb, Bs_h + dstbase);
            gload16(Bl + gb, Bs_l + dstbase);
        }
        __syncthreads();

#pragma unroll
        for (int kh = 0; kh < 4; ++kh) {            // K=16 slices
            const int cg = kh * 2 + (lane >> 5);
            f16x8 a_h[2], a_l[2], b_h[2], b_l[2];
#pragma unroll
            for (int i = 0; i < 2; ++i) {
                const int row = wm * 64 + i * 32 + (lane & 31);
                const int off = row * 64 + ((cg ^ (row & 7)) * 8);
                a_h[i] = *(const f16x8*)(As_h + off);
                a_l[i] = *(const f16x8*)(As_l + off);
            }
#pragma unroll
            for (int j = 0; j < 2; ++j) {
                const int col = wn * 64 + j * 32 + (lane & 31);
                const int off = col * 64 + ((cg ^ (col & 7)) * 8);
                b_h[j] = *(const f16x8*)(Bs_h + off);
                b_l[j] = *(const f16x8*)(Bs_l + off);
            }
            __builtin_amdgcn_s_setprio(1);
#pragma unroll
            for (int i = 0; i < 2; ++i)
#pragma unroll
                for (int j = 0; j < 2; ++j) {
                    acc[i][j] = __builtin_amdgcn_mfma_f32_32x32x16_f16(
                        a_h[i], b_h[j], acc[i][j], 0, 0, 0);
                    acc[i][j] = __builtin_amdgcn_mfma_f32_32x32x16_f16(
                        a_h[i], b_l[j], acc[i][j], 0, 0, 0);
                    acc[i][j] = __builtin_amdgcn_mfma_f32_32x32x16_f16(
                        a_l[i], b_h[j], acc[i][j], 0, 0, 0);
                }
            __builtin_amdgcn_s_setprio(0);
        }
        __syncthreads();
    }

    // epilogue: d = c2[n] - 2*dot, fused argmin.
    // C/D: row=(r&3)+8*(r>>2)+4*(lane>>5), col=lane&31.
    float bestv[2][16];
    int   besti[2][16];
#pragma unroll
    for (int i = 0; i < 2; ++i)
#pragma unroll
        for (int r = 0; r < 16; ++r) { bestv[i][r] = FLT_MAX; besti[i][r] = 0; }

#pragma unroll
    for (int j = 0; j < 2; ++j) {
        const int n = n0 + wn * 64 + j * 32 + (lane & 31);
        const float cn = c2[n];
#pragma unroll
        for (int i = 0; i < 2; ++i)
#pragma unroll
            for (int r = 0; r < 16; ++r) {
                float val = fmaf(-2.f, acc[i][j][r], cn);
                if (val < bestv[i][r] || (val == bestv[i][r] && n < besti[i][r])) {
                    bestv[i][r] = val; besti[i][r] = n;
                }
            }
    }

    const int chunk = ntile * 2 + wn;
#pragma unroll
    for (int i = 0; i < 2; ++i)
#pragma unroll
        for (int r = 0; r < 16; ++r) {
            float v = bestv[i][r];
            int  ix = besti[i][r];
#pragma unroll
            for (int off = 16; off >= 1; off >>= 1) {  // reduce within 32-lane half
                float ov = __shfl_xor(v, off, 64);
                int   oi = __shfl_xor(ix, off, 64);
                if (ov < v || (ov == v && oi < ix)) { v = ov; ix = oi; }
            }
            if ((lane & 31) == 0) {
                const int m = m0 + wm * 64 + i * 32 + (r & 3) + 8 * (r >> 2) + 4 * (lane >> 5);
                pval[(size_t)chunk * 16384 + m] = v;
                pidx[(size_t)chunk * 16384 + m] = ix;
            }
        }
}

// ------------------------------------------------------------- final token
__global__ __launch_bounds__(256) void token_reduce_kernel(
    const float* __restrict__ pval, const int* __restrict__ pidx,
    float* __restrict__ tok_out)
{
    const int m = blockIdx.x * 256 + threadIdx.x;
    float bv = pval[m];
    int   bi = pidx[m];
    for (int c = 1; c < 128; ++c) {
        float v = pval[(size_t)c * 16384 + m];
        int   i = pidx[(size_t)c * 16384 + m];
        if (v < bv || (v == bv && i < bi)) { bv = v; bi = i; }
    }
    tok_out[m] = (float)bi;
}

// --------------------------------------------------------------- gather
__global__ __launch_bounds__(192) void gather_kernel(
    const float* __restrict__ tok, const float* __restrict__ table,
    float* __restrict__ emb)
{
    const int m = blockIdx.x;
    const int t = threadIdx.x;
    const int token = (int)tok[m];
    const float4* src = (const float4*)(table + (size_t)token * 768);
    float4* dst = (float4*)(emb + (size_t)m * 768);
    dst[t] = src[t];
}

// ---------------------------------------------------------------- launch
extern "C" void kernel_launch(void* const* d_in, const int* in_sizes, int n_in,
                              void* d_out, int out_size, void* d_ws, size_t ws_size,
                              hipStream_t stream)
{
    const float* image = (const float*)d_in[0];
    const float* w1 = (const float*)d_in[1];
    const float* b1 = (const float*)d_in[2];
    const float* w2 = (const float*)d_in[3];
    const float* b2 = (const float*)d_in[4];
    const float* w3 = (const float*)d_in[5];
    const float* b3 = (const float*)d_in[6];
    const float* codebook = (const float*)d_in[7];
    const float* etab     = (const float*)d_in[8];

    float* out_tok = (float*)d_out;
    float* out_emb = (float*)d_out + 16384;

    char* ws = (char*)d_ws;

    const bool big = ws_size >= 214601728ull;   // 8-img conv2 chunks + all-16 conv3
    const bool mid = !big && ws_size >= 164270080ull;  // 4-img chunks + all-16 conv3

    if (big || mid) {
        const size_t F1PL = big ? 50331648ull : 25165824ull;  // per-plane f1 bytes
        const size_t F2OFF = 2 * F1PL;
        const size_t WOFF  = F2OFF + 100663296ull;

        unsigned short* f1h = (unsigned short*)ws;
        unsigned short* f1l = (unsigned short*)(ws + F1PL);
        unsigned short* Ah  = (unsigned short*)ws;
        unsigned short* Al  = (unsigned short*)(ws + 25165824);
        unsigned short* f2h = (unsigned short*)(ws + F2OFF);
        unsigned short* f2l = (unsigned short*)(ws + F2OFF + 50331648);
        unsigned short* Bh  = (unsigned short*)(ws + F2OFF);
        unsigned short* Bl  = (unsigned short*)(ws + F2OFF + 12582912);
        float* c2   = (float*)(ws + F2OFF + 25165824);
        float* pval = (float*)(ws + F2OFF + 25198592);
        int*   pidx = (int*)  (ws + F2OFF + 33587200);
        unsigned short* wr2h = (unsigned short*)(ws + WOFF);
        unsigned short* wr2l = (unsigned short*)(ws + WOFF + 1327104);
        unsigned short* wr3h = (unsigned short*)(ws + WOFF + 2654208);
        unsigned short* wr3l = (unsigned short*)(ws + WOFF + 7962624);
        unsigned short* zeros = (unsigned short*)(ws + WOFF + 13271040);

        zero_kernel<<<1, 256, 0, stream>>>(zeros);
        reorder_w_kernel<<<(384 * 9 * 24 + 255) / 256, 256, 0, stream>>>(w2, wr2h, wr2l, 384, 192);
        reorder_w_kernel<<<(768 * 9 * 48 + 255) / 256, 256, 0, stream>>>(w3, wr3h, wr3l, 768, 384);

        const int nbc = big ? 2 : 4;        // chunks
        const int nbi = big ? 8 : 4;        // images per chunk
        for (int bc = 0; bc < nbc; ++bc) {
            const int b0 = bc * nbi;
            const int total1 = nbi * (192 / 8) * 128 * (128 / 4);
            conv1_direct<3, 192, 256, 128>
                <<<total1 / 256, 256, 0, stream>>>(
                    image + (size_t)b0 * 3 * 256 * 256, w1, b1, f1h, f1l, nbi);
            conv_gemm<192, 384, 128, 64, 6, 12, true>
                <<<dim3(3, nbi * 32), 256, 0, stream>>>(
                    f1h, f1l, wr2h, wr2l, b2,
                    f2h + (size_t)b0 * 4096 * 384, f2l + (size_t)b0 * 4096 * 384, zeros);
        }
        conv_gemm<384, 768, 64, 32, 5, 10, false>
            <<<dim3(6, 128), 256, 0, stream>>>(f2h, f2l, wr3h, wr3l, b3, Ah, Al, zeros);

        split_codebook_kernel<<<2048, 256, 0, stream>>>(codebook, Bh, Bl, c2);
        vq_mfma_kernel<<<8192, 256, 0, stream>>>(Ah, Al, Bh, Bl, c2, pval, pidx);
        token_reduce_kernel<<<64, 256, 0, stream>>>(pval, pidx, out_tok);
        gather_kernel<<<16384, 192, 0, stream>>>(out_tok, etab, out_emb);
        return;
    }

    // ---- base layout (round-8 verified, peak 139,104,256 B) ----
    unsigned short* Ah  = (unsigned short*)ws;
    unsigned short* Al  = (unsigned short*)(ws + 25165824);
    unsigned short* f1h = (unsigned short*)(ws + 50331648);
    unsigned short* f1l = (unsigned short*)(ws + 75497472);
    unsigned short* Bh  = (unsigned short*)(ws + 50331648);
    unsigned short* Bl  = (unsigned short*)(ws + 62914560);
    float* c2   = (float*)(ws + 75497472);
    float* pval = (float*)(ws + 75530240);
    int*   pidx = (int*)  (ws + 83918848);
    unsigned short* f2h = (unsigned short*)(ws + 100663296);
    unsigned short* f2l = (unsigned short*)(ws + 113246208);
    unsigned short* wr2h = (unsigned short*)(ws + 125829120);
    unsigned short* wr2l = (unsigned short*)(ws + 127156224);
    unsigned short* wr3h = (unsigned short*)(ws + 128483328);
    unsigned short* wr3l = (unsigned short*)(ws + 133791744);
    unsigned short* zeros = (unsigned short*)(ws + 139100160);

    zero_kernel<<<1, 256, 0, stream>>>(zeros);
    reorder_w_kernel<<<(384 * 9 * 24 + 255) / 256, 256, 0, stream>>>(w2, wr2h, wr2l, 384, 192);
    reorder_w_kernel<<<(768 * 9 * 48 + 255) / 256, 256, 0, stream>>>(w3, wr3h, wr3l, 768, 384);

    for (int bc = 0; bc < 4; ++bc) {
        const int b0 = bc * 4;
        const int total1 = 4 * (192 / 8) * 128 * (128 / 4);
        conv1_direct<3, 192, 256, 128>
            <<<total1 / 256, 256, 0, stream>>>(
                image + (size_t)b0 * 3 * 256 * 256, w1, b1, f1h, f1l, 4);
        conv_gemm<192, 384, 128, 64, 6, 12, true>
            <<<dim3(3, 128), 256, 0, stream>>>(
                f1h, f1l, wr2h, wr2l, b2, f2h, f2l, zeros);
        conv_gemm<384, 768, 64, 32, 5, 10, false>
            <<<dim3(6, 32), 256, 0, stream>>>(
                f2h, f2l, wr3h, wr3l, b3,
                Ah + (size_t)b0 * 1024 * 768, Al + (size_t)b0 * 1024 * 768, zeros);
    }

    split_codebook_kernel<<<2048, 256, 0, stream>>>(codebook, Bh, Bl, c2);
    vq_mfma_kernel<<<8192, 256, 0, stream>>>(Ah, Al, Bh, Bl, c2, pval, pidx);
    token_reduce_kernel<<<64, 256, 0, stream>>>(pval, pidx, out_tok);
    gather_kernel<<<16384, 192, 0, stream>>>(out_tok, etab, out_emb);
}

// Round 11
// 1278.655 us; speedup vs baseline: 1.2265x; 1.2265x over previous
//
#include <hip/hip_runtime.h>
#include <hip/hip_bf16.h>
#include <float.h>

// image [16,3,256,256] -> conv1(3->192,s2)+relu -> conv2(192->384,s2)+relu
// -> conv3(384->768,s2) -> feats [16384,768] -> argmin over 8192 codes -> gather.
// conv2/conv3/VQ run as split-FP16 MFMA GEMMs: x = hi + lo, dot = ah*bh + ah*bl
// + al*bh (per-term error ~2^-22), on v_mfma_f32_16x16x32_f16.
// NOTE (r10 lesson): 16x16 fragments are REQUIRED here -- with 64-halfword LDS
// rows, 32x32 fragments force >=4 lanes per physical k-chunk = unavoidable
// 4-way bank conflict (measured: 5e7 conflicts, MfmaUtil 46->33%).
// Launcher picks chunking by ws_size (big: conv2 2x8-img chunks, conv3 all-16).

typedef __attribute__((ext_vector_type(4))) float f32x4;
typedef __attribute__((ext_vector_type(8))) _Float16 f16x8;
typedef __attribute__((ext_vector_type(8))) unsigned short u16x8;

__device__ __forceinline__ void split_f16(float x, unsigned short& hb, unsigned short& lb) {
    _Float16 h = (_Float16)x;                    // RNE fp32->fp16
    _Float16 l = (_Float16)(x - (float)h);       // residual, ~2^-12|x|
    hb = __builtin_bit_cast(unsigned short, h);
    lb = __builtin_bit_cast(unsigned short, l);
}

__device__ __forceinline__ void gload16(const void* g, const unsigned short* l) {
    typedef unsigned int __attribute__((address_space(1))) g_u32;
    typedef unsigned int __attribute__((address_space(3))) l_u32;
    __builtin_amdgcn_global_load_lds((const g_u32*)g, (l_u32*)l, 16, 0, 0);
}

// ------------------------------------------------------------- zero page
__global__ __launch_bounds__(256) void zero_kernel(unsigned short* z) {
    u16x8 v = {0, 0, 0, 0, 0, 0, 0, 0};
    *(u16x8*)&z[threadIdx.x * 8] = v;           // 4 KB
}

// -------------------------------------------------- weight reorder+split
__global__ __launch_bounds__(256) void reorder_w_kernel(
    const float* __restrict__ w, unsigned short* __restrict__ wh,
    unsigned short* __restrict__ wl, int COUT, int CIN)
{
    const int t = blockIdx.x * 256 + threadIdx.x;
    const int c8n = CIN / 8;
    const int total = COUT * 9 * c8n;
    if (t >= total) return;
    const int c8 = t % c8n;
    const int tap = (t / c8n) % 9;
    const int o = t / (9 * c8n);
    u16x8 vh, vl;
#pragma unroll
    for (int k = 0; k < 8; ++k) {
        const int c = c8 * 8 + k;
        unsigned short hb, lb;
        split_f16(w[((size_t)o * CIN + c) * 9 + tap], hb, lb);
        vh[k] = hb; vl[k] = lb;
    }
    const size_t dst = ((size_t)o * 9 + tap) * CIN + c8 * 8;
    *(u16x8*)&wh[dst] = vh;
    *(u16x8*)&wl[dst] = vl;
}

// --------------------------------- conv1: direct fp32, NHWC fp16 hi/lo out
template <int CIN, int COUT, int HIN, int HOUT>
__global__ __launch_bounds__(256) void conv1_direct(
    const float* __restrict__ in,   // [nb][CIN][HIN][HIN] (chunk-local)
    const float* __restrict__ w, const float* __restrict__ bias,
    unsigned short* __restrict__ ah, unsigned short* __restrict__ al, int nb)
{
    constexpr int WIN = HIN, WOUT = HOUT;
    constexpr int NXT = WOUT / 4;
    constexpr int NOT = COUT / 8;
    int t = blockIdx.x * 256 + threadIdx.x;
    const int total = nb * NOT * HOUT * NXT;
    if (t >= total) return;

    const int xt = t % NXT;
    const int y  = (t / NXT) % HOUT;
    int ot = (t / (NXT * HOUT)) % NOT;          // wave-uniform
    int bl = t / (NXT * HOUT * NOT);            // wave-uniform
    ot = __builtin_amdgcn_readfirstlane(ot);
    bl = __builtin_amdgcn_readfirstlane(bl);

    const int x0 = xt * 4, o0 = ot * 8;
    float acc[8][4];
#pragma unroll
    for (int i = 0; i < 8; ++i) {
        float bv = bias[o0 + i];
#pragma unroll
        for (int j = 0; j < 4; ++j) acc[i][j] = bv;
    }

    const float* inb = in + (size_t)bl * CIN * HIN * WIN;
    const float* wb  = w + (size_t)o0 * CIN * 9;

    for (int c = 0; c < CIN; ++c) {
        const float* inc = inb + (size_t)c * HIN * WIN;
#pragma unroll
        for (int ky = 0; ky < 3; ++ky) {
            const int iy = 2 * y - 1 + ky;
            if ((unsigned)iy < (unsigned)HIN) {
                const float* row = inc + (size_t)iy * WIN;
                const int sx0 = 2 * x0 - 1;
                float xin[9];
                xin[0] = (sx0 >= 0) ? row[sx0] : 0.f;
#pragma unroll
                for (int k = 1; k < 9; ++k) xin[k] = row[sx0 + k];
#pragma unroll
                for (int i = 0; i < 8; ++i) {
                    const float* wr = wb + ((size_t)i * CIN + c) * 9 + ky * 3;
                    const float w0 = wr[0], w1 = wr[1], w2 = wr[2];
#pragma unroll
                    for (int j = 0; j < 4; ++j)
                        acc[i][j] = fmaf(w0, xin[2 * j],
                                    fmaf(w1, xin[2 * j + 1],
                                    fmaf(w2, xin[2 * j + 2], acc[i][j])));
                }
            }
        }
    }

#pragma unroll
    for (int j = 0; j < 4; ++j) {
        u16x8 vh, vl;
#pragma unroll
        for (int i = 0; i < 8; ++i) {
            unsigned short hb, lb;
            split_f16(fmaxf(acc[i][j], 0.f), hb, lb);
            vh[i] = hb; vl[i] = lb;
        }
        const size_t m = (size_t)bl * (HOUT * WOUT) + (size_t)y * WOUT + x0 + j;
        *(u16x8*)&ah[m * COUT + o0] = vh;
        *(u16x8*)&al[m * COUT + o0] = vl;
    }
}

// --------------------------- conv2/conv3: implicit-GEMM split-fp16 MFMA
template <int CIN, int COUT, int HIN, int HOUT, int LOGW, int LOGHW, bool RELU>
__global__ __launch_bounds__(256) void conv_gemm(
    const unsigned short* __restrict__ inh, const unsigned short* __restrict__ inl,
    const unsigned short* __restrict__ wrh, const unsigned short* __restrict__ wrl,
    const float* __restrict__ bias,
    unsigned short* __restrict__ outh, unsigned short* __restrict__ outl,
    const unsigned short* __restrict__ zeros)
{
    constexpr int WIN = HIN, WOUT = HOUT;
    constexpr int KCPT = CIN / 64;
    constexpr int NSTEP = 9 * KCPT;

    __shared__ unsigned short lds[32768];       // 64 KB
    unsigned short* As_h = lds;
    unsigned short* As_l = lds + 8192;
    unsigned short* Bs_h = lds + 16384;
    unsigned short* Bs_l = lds + 24576;

    const int tid  = threadIdx.x;
    const int lane = tid & 63;
    const int wid  = tid >> 6;
    const int ntile = blockIdx.x, mtile = blockIdx.y;
    const int m0 = mtile * 128, n0 = ntile * 128;
    const int wm = wid >> 1, wn = wid & 1;

    int aoff0[4], boff0[4], yv[4], xv[4], dstb[4];
#pragma unroll
    for (int p = 0; p < 4; ++p) {
        const int s = wid * 64 + p * 256 + lane;   // slot 0..1023
        const int r = s >> 3;                       // row 0..127
        const int cl = (s & 7) ^ (r & 7);           // logical k-chunk
        const int m = m0 + r;
        const int b = m >> LOGHW;
        const int y = (m >> LOGW) & (HOUT - 1);
        const int x = m & (WOUT - 1);
        yv[p] = y; xv[p] = x;
        aoff0[p] = ((b * HIN + 2 * y) * WIN + 2 * x) * CIN + cl * 8;
        boff0[p] = (n0 + r) * 9 * CIN + cl * 8;
        dstb[p] = (wid * 64 + p * 256) * 8;
    }

    f32x4 acc[4][4];
#pragma unroll
    for (int i = 0; i < 4; ++i)
#pragma unroll
        for (int j = 0; j < 4; ++j) acc[i][j] = f32x4{0.f, 0.f, 0.f, 0.f};

    for (int ks = 0; ks < NSTEP; ++ks) {
        const int tap = ks / KCPT;
        const int c0 = (ks % KCPT) * 64;
        const int ky = tap / 3, kx = tap - ky * 3;
        const int doff = ((ky - 1) * WIN + (kx - 1)) * CIN + c0;

#pragma unroll
        for (int p = 0; p < 4; ++p) {
            const bool valid = !((yv[p] == 0 && ky == 0) || (xv[p] == 0 && kx == 0));
            const unsigned short* sa_h = valid ? inh + (aoff0[p] + doff) : zeros;
            const unsigned short* sa_l = valid ? inl + (aoff0[p] + doff) : zeros;
            gload16(sa_h, As_h + dstb[p]);
            gload16(sa_l, As_l + dstb[p]);
            const int bo = boff0[p] + tap * CIN + c0;
            gload16(wrh + bo, Bs_h + dstb[p]);
            gload16(wrl + bo, Bs_l + dstb[p]);
        }
        __syncthreads();

#pragma unroll
        for (int kh = 0; kh < 2; ++kh) {
            const int cg = kh * 4 + (lane >> 4);
            f16x8 a_h[4], a_l[4], b_h[4], b_l[4];
#pragma unroll
            for (int i = 0; i < 4; ++i) {
                const int row = wm * 64 + i * 16 + (lane & 15);
                const int off = row * 64 + ((cg ^ (row & 7)) * 8);
                a_h[i] = *(const f16x8*)(As_h + off);
                a_l[i] = *(const f16x8*)(As_l + off);
            }
#pragma unroll
            for (int j = 0; j < 4; ++j) {
                const int col = wn * 64 + j * 16 + (lane & 15);
                const int off = col * 64 + ((cg ^ (col & 7)) * 8);
                b_h[j] = *(const f16x8*)(Bs_h + off);
                b_l[j] = *(const f16x8*)(Bs_l + off);
            }
            __builtin_amdgcn_s_setprio(1);
#pragma unroll
            for (int i = 0; i < 4; ++i)
#pragma unroll
                for (int j = 0; j < 4; ++j) {
                    acc[i][j] = __builtin_amdgcn_mfma_f32_16x16x32_f16(
                        a_h[i], b_h[j], acc[i][j], 0, 0, 0);
                    acc[i][j] = __builtin_amdgcn_mfma_f32_16x16x32_f16(
                        a_h[i], b_l[j], acc[i][j], 0, 0, 0);
                    acc[i][j] = __builtin_amdgcn_mfma_f32_16x16x32_f16(
                        a_l[i], b_h[j], acc[i][j], 0, 0, 0);
                }
            __builtin_amdgcn_s_setprio(0);
        }
        __syncthreads();
    }

    float bv4[4];
#pragma unroll
    for (int j = 0; j < 4; ++j) bv4[j] = bias[n0 + wn * 64 + j * 16 + (lane & 15)];
#pragma unroll
    for (int i = 0; i < 4; ++i)
#pragma unroll
        for (int r = 0; r < 4; ++r) {
            const size_t m = m0 + wm * 64 + i * 16 + (lane >> 4) * 4 + r;
#pragma unroll
            for (int j = 0; j < 4; ++j) {
                const int n = n0 + wn * 64 + j * 16 + (lane & 15);
                float v = acc[i][j][r] + bv4[j];
                if (RELU) v = fmaxf(v, 0.f);
                unsigned short hb, lb;
                split_f16(v, hb, lb);
                outh[m * COUT + n] = hb;
                outl[m * COUT + n] = lb;
            }
        }
}

// -------------------------------------------- codebook split + norms
__global__ __launch_bounds__(256) void split_codebook_kernel(
    const float* __restrict__ cb, unsigned short* __restrict__ bh,
    unsigned short* __restrict__ bl, float* __restrict__ c2)
{
    const int v = blockIdx.x * 4 + (threadIdx.x >> 6);
    const int lane = threadIdx.x & 63;
    const float* row = cb + (size_t)v * 768;
    float s = 0.f;
#pragma unroll
    for (int t = 0; t < 12; ++t) {
        const int idx = lane + 64 * t;
        float x = row[idx];
        s = fmaf(x, x, s);
        unsigned short hb, lb;
        split_f16(x, hb, lb);
        bh[(size_t)v * 768 + idx] = hb;
        bl[(size_t)v * 768 + idx] = lb;
    }
#pragma unroll
    for (int off = 32; off >= 1; off >>= 1) s += __shfl_xor(s, off, 64);
    if (lane == 0) c2[v] = s;
}

// --------------------------------------- VQ: split-fp16 MFMA GEMM + argmin
__global__ __launch_bounds__(256) void vq_mfma_kernel(
    const unsigned short* __restrict__ Ah, const unsigned short* __restrict__ Al,
    const unsigned short* __restrict__ Bh, const unsigned short* __restrict__ Bl,
    const float* __restrict__ c2,
    float* __restrict__ pval, int* __restrict__ pidx)
{
    __shared__ unsigned short lds[32768];
    unsigned short* As_h = lds;
    unsigned short* As_l = lds + 8192;
    unsigned short* Bs_h = lds + 16384;
    unsigned short* Bs_l = lds + 24576;

    const int tid  = threadIdx.x;
    const int lane = tid & 63;
    const int wid  = tid >> 6;

    const int bid    = blockIdx.x;
    const int xcd    = bid & 7;
    const int local  = bid >> 3;
    const int msuper = local >> 5;
    const int idx5   = local & 31;
    const int mtile  = msuper * 4 + (idx5 & 3);
    const int ntile  = xcd * 8 + (idx5 >> 2);

    const int m0 = mtile * 128, n0 = ntile * 128;
    const int wm = wid >> 1, wn = wid & 1;

    f32x4 acc[4][4];
#pragma unroll
    for (int i = 0; i < 4; ++i)
#pragma unroll
        for (int j = 0; j < 4; ++j) acc[i][j] = f32x4{0.f, 0.f, 0.f, 0.f};

    for (int step = 0; step < 12; ++step) {
        const int kb = step * 64;
#pragma unroll
        for (int p = 0; p < 4; ++p) {
            const int s  = wid * 64 + p * 256 + lane;
            const int r  = s >> 3;
            const int cl = (s & 7) ^ (r & 7);
            const int dstbase = (wid * 64 + p * 256) * 8;
            const size_t ga = (size_t)(m0 + r) * 768 + kb + cl * 8;
            const size_t gb = (size_t)(n0 + r) * 768 + kb + cl * 8;
            gload16(Ah + ga, As_h + dstbase);
            gload16(Al + ga, As_l + dstbase);
            gload16(Bh + gb, Bs_h + dstbase);
            gload16(Bl + gb, Bs_l + dstbase);
        }
        __syncthreads();

#pragma unroll
        for (int kh = 0; kh < 2; ++kh) {
            const int cg = kh * 4 + (lane >> 4);
            f16x8 a_h[4], a_l[4], b_h[4], b_l[4];
#pragma unroll
            for (int i = 0; i < 4; ++i) {
                const int row = wm * 64 + i * 16 + (lane & 15);
                const int off = row * 64 + ((cg ^ (row & 7)) * 8);
                a_h[i] = *(const f16x8*)(As_h + off);
                a_l[i] = *(const f16x8*)(As_l + off);
            }
#pragma unroll
            for (int j = 0; j < 4; ++j) {
                const int col = wn * 64 + j * 16 + (lane & 15);
                const int off = col * 64 + ((cg ^ (col & 7)) * 8);
                b_h[j] = *(const f16x8*)(Bs_h + off);
                b_l[j] = *(const f16x8*)(Bs_l + off);
            }
            __builtin_amdgcn_s_setprio(1);
#pragma unroll
            for (int i = 0; i < 4; ++i)
#pragma unroll
                for (int j = 0; j < 4; ++j) {
                    acc[i][j] = __builtin_amdgcn_mfma_f32_16x16x32_f16(
                        a_h[i], b_h[j], acc[i][j], 0, 0, 0);
                    acc[i][j] = __builtin_amdgcn_mfma_f32_16x16x32_f16(
                        a_h[i], b_l[j], acc[i][j], 0, 0, 0);
                    acc[i][j] = __builtin_amdgcn_mfma_f32_16x16x32_f16(
                        a_l[i], b_h[j], acc[i][j], 0, 0, 0);
                }
            __builtin_amdgcn_s_setprio(0);
        }
        __syncthreads();
    }

    float bestv[4][4];
    int   besti[4][4];
#pragma unroll
    for (int i = 0; i < 4; ++i)
#pragma unroll
        for (int r = 0; r < 4; ++r) { bestv[i][r] = FLT_MAX; besti[i][r] = 0; }

#pragma unroll
    for (int j = 0; j < 4; ++j) {
        const int n = n0 + wn * 64 + j * 16 + (lane & 15);
        const float cn = c2[n];
#pragma unroll
        for (int i = 0; i < 4; ++i)
#pragma unroll
            for (int r = 0; r < 4; ++r) {
                float val = fmaf(-2.f, acc[i][j][r], cn);
                if (val < bestv[i][r] || (val == bestv[i][r] && n < besti[i][r])) {
                    bestv[i][r] = val; besti[i][r] = n;
                }
            }
    }

    const int chunk = ntile * 2 + wn;
#pragma unroll
    for (int i = 0; i < 4; ++i)
#pragma unroll
        for (int r = 0; r < 4; ++r) {
            float v = bestv[i][r];
            int  ix = besti[i][r];
#pragma unroll
            for (int off = 8; off >= 1; off >>= 1) {
                float ov = __shfl_xor(v, off, 64);
                int   oi = __shfl_xor(ix, off, 64);
                if (ov < v || (ov == v && oi < ix)) { v = ov; ix = oi; }
            }
            if ((lane & 15) == 0) {
                const int m = m0 + wm * 64 + i * 16 + (lane >> 4) * 4 + r;
                pval[(size_t)chunk * 16384 + m] = v;
                pidx[(size_t)chunk * 16384 + m] = ix;
            }
        }
}

// ------------------------------------------------------------- final token
__global__ __launch_bounds__(256) void token_reduce_kernel(
    const float* __restrict__ pval, const int* __restrict__ pidx,
    float* __restrict__ tok_out)
{
    const int m = blockIdx.x * 256 + threadIdx.x;
    float bv = pval[m];
    int   bi = pidx[m];
    for (int c = 1; c < 128; ++c) {
        float v = pval[(size_t)c * 16384 + m];
        int   i = pidx[(size_t)c * 16384 + m];
        if (v < bv || (v == bv && i < bi)) { bv = v; bi = i; }
    }
    tok_out[m] = (float)bi;
}

// --------------------------------------------------------------- gather
__global__ __launch_bounds__(192) void gather_kernel(
    const float* __restrict__ tok, const float* __restrict__ table,
    float* __restrict__ emb)
{
    const int m = blockIdx.x;
    const int t = threadIdx.x;
    const int token = (int)tok[m];
    const float4* src = (const float4*)(table + (size_t)token * 768);
    float4* dst = (float4*)(emb + (size_t)m * 768);
    dst[t] = src[t];
}

// ---------------------------------------------------------------- launch
extern "C" void kernel_launch(void* const* d_in, const int* in_sizes, int n_in,
                              void* d_out, int out_size, void* d_ws, size_t ws_size,
                              hipStream_t stream)
{
    const float* image = (const float*)d_in[0];
    const float* w1 = (const float*)d_in[1];
    const float* b1 = (const float*)d_in[2];
    const float* w2 = (const float*)d_in[3];
    const float* b2 = (const float*)d_in[4];
    const float* w3 = (const float*)d_in[5];
    const float* b3 = (const float*)d_in[6];
    const float* codebook = (const float*)d_in[7];
    const float* etab     = (const float*)d_in[8];

    float* out_tok = (float*)d_out;
    float* out_emb = (float*)d_out + 16384;

    char* ws = (char*)d_ws;

    const bool big = ws_size >= 214601728ull;   // 8-img conv2 chunks + all-16 conv3
    const bool mid = !big && ws_size >= 164270080ull;  // 4-img chunks + all-16 conv3

    if (big || mid) {
        const size_t F1PL = big ? 50331648ull : 25165824ull;  // per-plane f1 bytes
        const size_t F2OFF = 2 * F1PL;
        const size_t WOFF  = F2OFF + 100663296ull;

        unsigned short* f1h = (unsigned short*)ws;
        unsigned short* f1l = (unsigned short*)(ws + F1PL);
        unsigned short* Ah  = (unsigned short*)ws;
        unsigned short* Al  = (unsigned short*)(ws + 25165824);
        unsigned short* f2h = (unsigned short*)(ws + F2OFF);
        unsigned short* f2l = (unsigned short*)(ws + F2OFF + 50331648);
        unsigned short* Bh  = (unsigned short*)(ws + F2OFF);
        unsigned short* Bl  = (unsigned short*)(ws + F2OFF + 12582912);
        float* c2   = (float*)(ws + F2OFF + 25165824);
        float* pval = (float*)(ws + F2OFF + 25198592);
        int*   pidx = (int*)  (ws + F2OFF + 33587200);
        unsigned short* wr2h = (unsigned short*)(ws + WOFF);
        unsigned short* wr2l = (unsigned short*)(ws + WOFF + 1327104);
        unsigned short* wr3h = (unsigned short*)(ws + WOFF + 2654208);
        unsigned short* wr3l = (unsigned short*)(ws + WOFF + 7962624);
        unsigned short* zeros = (unsigned short*)(ws + WOFF + 13271040);

        zero_kernel<<<1, 256, 0, stream>>>(zeros);
        reorder_w_kernel<<<(384 * 9 * 24 + 255) / 256, 256, 0, stream>>>(w2, wr2h, wr2l, 384, 192);
        reorder_w_kernel<<<(768 * 9 * 48 + 255) / 256, 256, 0, stream>>>(w3, wr3h, wr3l, 768, 384);

        const int nbc = big ? 2 : 4;        // chunks
        const int nbi = big ? 8 : 4;        // images per chunk
        for (int bc = 0; bc < nbc; ++bc) {
            const int b0 = bc * nbi;
            const int total1 = nbi * (192 / 8) * 128 * (128 / 4);
            conv1_direct<3, 192, 256, 128>
                <<<total1 / 256, 256, 0, stream>>>(
                    image + (size_t)b0 * 3 * 256 * 256, w1, b1, f1h, f1l, nbi);
            conv_gemm<192, 384, 128, 64, 6, 12, true>
                <<<dim3(3, nbi * 32), 256, 0, stream>>>(
                    f1h, f1l, wr2h, wr2l, b2,
                    f2h + (size_t)b0 * 4096 * 384, f2l + (size_t)b0 * 4096 * 384, zeros);
        }
        conv_gemm<384, 768, 64, 32, 5, 10, false>
            <<<dim3(6, 128), 256, 0, stream>>>(f2h, f2l, wr3h, wr3l, b3, Ah, Al, zeros);

        split_codebook_kernel<<<2048, 256, 0, stream>>>(codebook, Bh, Bl, c2);
        vq_mfma_kernel<<<8192, 256, 0, stream>>>(Ah, Al, Bh, Bl, c2, pval, pidx);
        token_reduce_kernel<<<64, 256, 0, stream>>>(pval, pidx, out_tok);
        gather_kernel<<<16384, 192, 0, stream>>>(out_tok, etab, out_emb);
        return;
    }

    // ---- base layout (round-8 verified, peak 139,104,256 B) ----
    unsigned short* Ah  = (unsigned short*)ws;
    unsigned short* Al  = (unsigned short*)(ws + 25165824);
    unsigned short* f1h = (unsigned short*)(ws + 50331648);
    unsigned short* f1l = (unsigned short*)(ws + 75497472);
    unsigned short* Bh  = (unsigned short*)(ws + 50331648);
    unsigned short* Bl  = (unsigned short*)(ws + 62914560);
    float* c2   = (float*)(ws + 75497472);
    float* pval = (float*)(ws + 75530240);
    int*   pidx = (int*)  (ws + 83918848);
    unsigned short* f2h = (unsigned short*)(ws + 100663296);
    unsigned short* f2l = (unsigned short*)(ws + 113246208);
    unsigned short* wr2h = (unsigned short*)(ws + 125829120);
    unsigned short* wr2l = (unsigned short*)(ws + 127156224);
    unsigned short* wr3h = (unsigned short*)(ws + 128483328);
    unsigned short* wr3l = (unsigned short*)(ws + 133791744);
    unsigned short* zeros = (unsigned short*)(ws + 139100160);

    zero_kernel<<<1, 256, 0, stream>>>(zeros);
    reorder_w_kernel<<<(384 * 9 * 24 + 255) / 256, 256, 0, stream>>>(w2, wr2h, wr2l, 384, 192);
    reorder_w_kernel<<<(768 * 9 * 48 + 255) / 256, 256, 0, stream>>>(w3, wr3h, wr3l, 768, 384);

    for (int bc = 0; bc < 4; ++bc) {
        const int b0 = bc * 4;
        const int total1 = 4 * (192 / 8) * 128 * (128 / 4);
        conv1_direct<3, 192, 256, 128>
            <<<total1 / 256, 256, 0, stream>>>(
                image + (size_t)b0 * 3 * 256 * 256, w1, b1, f1h, f1l, 4);
        conv_gemm<192, 384, 128, 64, 6, 12, true>
            <<<dim3(3, 128), 256, 0, stream>>>(
                f1h, f1l, wr2h, wr2l, b2, f2h, f2l, zeros);
        conv_gemm<384, 768, 64, 32, 5, 10, false>
            <<<dim3(6, 32), 256, 0, stream>>>(
                f2h, f2l, wr3h, wr3l, b3,
                Ah + (size_t)b0 * 1024 * 768, Al + (size_t)b0 * 1024 * 768, zeros);
    }

    split_codebook_kernel<<<2048, 256, 0, stream>>>(codebook, Bh, Bl, c2);
    vq_mfma_kernel<<<8192, 256, 0, stream>>>(Ah, Al, Bh, Bl, c2, pval, pidx);
    token_reduce_kernel<<<64, 256, 0, stream>>>(pval, pidx, out_tok);
    gather_kernel<<<16384, 192, 0, stream>>>(out_tok, etab, out_emb);
}